// Round 6
// baseline (265.389 us; speedup 1.0000x reference)
//
#include <hip/hip_runtime.h>

#define N_NODES 50000
#define N_EDGES 800000
#define D 128
#define CAP 48                        // max in-degree slots (verified sufficient R2-R8)

#define FILLB (N_EDGES / 256)         // 3125 fill blocks (exact), one edge per thread
#define PACKB 24                      // W-pack blocks (96 wids)

typedef __attribute__((ext_vector_type(4))) float f32x4;
typedef __attribute__((ext_vector_type(8))) short s16x8;

__device__ inline unsigned short f32_to_bf16_rtne(float f) {
    union { float f; unsigned u; } c; c.f = f;
    unsigned u = c.u;
    u += 0x7FFF + ((u >> 16) & 1);
    return (unsigned short)(u >> 16);
}
__device__ inline float bf16_to_f32(unsigned short h) {
    union { unsigned u; float f; } c; c.u = ((unsigned)h) << 16;
    return c.f;
}
__device__ inline unsigned pack_bf2(float a, float b) {
    return (unsigned)f32_to_bf16_rtne(a) | ((unsigned)f32_to_bf16_rtne(b) << 16);
}
__device__ inline void unpack_bf2(unsigned u, float& a, float& b) {
    union { unsigned u; float f; } c0, c1;
    c0.u = u << 16; c1.u = u & 0xFFFF0000u;
    a = c0.f; b = c1.f;
}
__device__ inline void acc_uint4(uint4 v, float* a) {
    float f0, f1;
    unpack_bf2(v.x, f0, f1); a[0] += f0; a[1] += f1;
    unpack_bf2(v.y, f0, f1); a[2] += f0; a[3] += f1;
    unpack_bf2(v.z, f0, f1); a[4] += f0; a[5] += f1;
    unpack_bf2(v.w, f0, f1); a[6] += f0; a[7] += f1;
}

// ---------------- build: one pass over edges, plain u16 slot stores ----------------
// R0-R4 lessons: (1) scattered sub-line global ops (store OR atomic) cost ~40ns HBM-pipe
// each, ~one line writeback per op -- ~65-75us at this structure, invariant across 4
// variants (plain store / atomicOr / XCD-partitioned / XCD-self-identified); (2) R4's
// counting-sort build was 2.3x faster but changed slot-ordering statistics and tripped
// the replay numerics check -- fill ordering mechanism is FROZEN in this exact form.

__global__ __launch_bounds__(256) void build_fill(const int* __restrict__ src,
                                                  const int* __restrict__ dst,
                                                  int* __restrict__ cursor,
                                                  int* __restrict__ odeg,
                                                  unsigned short* __restrict__ slots,
                                                  const float* __restrict__ W0,
                                                  const float* __restrict__ W1,
                                                  const float* __restrict__ W2,
                                                  s16x8* __restrict__ wpk) {
    int b = blockIdx.x;
    if (b < FILLB) {
        int e = b * 256 + threadIdx.x;
        int s = src[e];
        int d = dst[e];
        atomicAdd(&odeg[s], 1);                       // fire-and-forget
        int pos = atomicAdd(&cursor[d], 1);
        if (pos < CAP) slots[d * CAP + pos] = (unsigned short)s;
    } else {
        // ---- W-pack role ----
        int wid = (b - FILLB) * 4 + (threadIdx.x >> 6);   // 0..95 = layer(3) x ct(8) x ks(4)
        if (wid >= 96) return;
        int lane = threadIdx.x & 63;
        int layer = wid / 32, rem = wid % 32;
        int ct = rem >> 2, ks = rem & 3;
        const float* W = (layer == 0) ? W0 : (layer == 1) ? W1 : W2;
        int col = ct * 16 + (lane & 15);
        int k0  = ks * 32 + (lane >> 4) * 8;
        s16x8 hi, lo;
#pragma unroll
        for (int j = 0; j < 8; j++) {
            float w = W[(k0 + j) * D + col];
            unsigned short h = f32_to_bf16_rtne(w);
            hi[j] = (short)h;
            lo[j] = (short)f32_to_bf16_rtne(w - bf16_to_f32(h));
        }
        int idx = layer * 4096 + (ct * 4 + ks) * 64 + lane;
        wpk[idx]        = hi;
        wpk[idx + 2048] = lo;
    }
}

// ---------------- h -> bf16 rows pre-scaled by s_out (computed in-kernel from odeg) ----------------

__global__ __launch_bounds__(256) void hconv(const float4* __restrict__ h,
                                             const int* __restrict__ odeg,
                                             float* __restrict__ s_out,
                                             uint2* __restrict__ hbA,
                                             uint2* __restrict__ hbB) {
    int gid = blockIdx.x * 256 + threadIdx.x;   // one float4 (4 channels) per thread
    const int total = N_NODES * 32;
    if (gid < total) {
        int node = gid >> 5;
        float so = rsqrtf(fmaxf((float)odeg[node], 1.0f));
        if ((gid & 31) == 0) s_out[node] = so;   // persist for fused_layer epilogue
        float4 v = h[gid];
        hbA[gid] = make_uint2(pack_bf2(so * v.x, so * v.y), pack_bf2(so * v.z, so * v.w));
    } else if (gid < total + 32) {
        hbA[total + (gid - total)] = make_uint2(0u, 0u);        // zero row of actA
    } else if (gid < total + 64) {
        hbB[total + (gid - total - 32)] = make_uint2(0u, 0u);   // zero row of actB
    }
}

// ---------------- fused layer: gather-aggregate -> LDS(split-bf16) -> MFMA GEMM ----------------
// Phase 1: 16 lanes/node; slot indices prefetched (OOB -> zero row at N_NODES);
//          rounds of 8 independent 16B gathers, no tails; s_in from deg in-kernel.
//          NEW (R6): the hi/lo split conversion happens HERE, once per value, and LDS
//          holds packed s16x8 planes -- phase 2 previously re-converted the same A
//          values in all 4 waves (4x redundant, ~55K lane-ops/block eliminated).
//          Arithmetic identical (f32 LDS roundtrip was exact) -> bit-identical output.
// Phase 2: 4 waves x 2 col-tiles; per ks: 2 ds_read_b128 + 4 B-loads + 6 MFMA.
//          acc = mh*Wh + ml*Wh + mh*Wl (B-frags from wpk, L2-resident).
// LDS geometry: [16 rows][17 chunks] s16x8, pad 16->17: phase-2 read lanes (arow 0..15,
// fixed chunk) stride 68 dwords -> banks 4*arow%32, 2-way alias = free (m136).

__global__ __launch_bounds__(256) void fused_layer(const uint4* __restrict__ x,
                                                   const unsigned short* __restrict__ slots,
                                                   const int* __restrict__ deg,
                                                   const s16x8* __restrict__ wpk,
                                                   const float* __restrict__ bias,
                                                   const float* __restrict__ s_out,
                                                   float* __restrict__ outf,
                                                   unsigned short* __restrict__ outb) {
    __shared__ s16x8 mHI[16 * 17];
    __shared__ s16x8 mLO[16 * 17];
    int tid = threadIdx.x;
    int row0 = blockIdx.x * 16;

    // ---- phase 1: aggregate ----
    {
        int nloc = tid >> 4;          // local node 0..15
        int l    = tid & 15;          // chunk: channels l*8 .. l*8+7
        int node = row0 + nloc;
        int dgraw = deg[node];
        int dg = min(dgraw, CAP);
        int base = node * CAP;
        // prefetch all slot indices; OOB -> zero row
        int idx0 = (l      < dg) ? (int)slots[base + l]      : N_NODES;
        int idx1 = (16 + l < dg) ? (int)slots[base + 16 + l] : N_NODES;
        int idx2 = (32 + l < dg) ? (int)slots[base + 32 + l] : N_NODES;

        float a[8];
#pragma unroll
        for (int j = 0; j < 8; j++) a[j] = 0.f;

        int nr = (dg + 7) >> 3;       // rounds of 8 (0..6), no tails
        for (int r = 0; r < nr; r++) {
            int c = r >> 1;
            int v = (c == 0) ? idx0 : ((c == 1) ? idx1 : idx2);
            int k = (r & 1) * 8;
            int s0 = __shfl(v, k + 0, 16), s1 = __shfl(v, k + 1, 16);
            int s2 = __shfl(v, k + 2, 16), s3 = __shfl(v, k + 3, 16);
            int s4 = __shfl(v, k + 4, 16), s5 = __shfl(v, k + 5, 16);
            int s6 = __shfl(v, k + 6, 16), s7 = __shfl(v, k + 7, 16);
            uint4 g0 = x[s0 * 16 + l];
            uint4 g1 = x[s1 * 16 + l];
            uint4 g2 = x[s2 * 16 + l];
            uint4 g3 = x[s3 * 16 + l];
            uint4 g4 = x[s4 * 16 + l];
            uint4 g5 = x[s5 * 16 + l];
            uint4 g6 = x[s6 * 16 + l];
            uint4 g7 = x[s7 * 16 + l];
            acc_uint4(g0, a); acc_uint4(g1, a); acc_uint4(g2, a); acc_uint4(g3, a);
            acc_uint4(g4, a); acc_uint4(g5, a); acc_uint4(g6, a); acc_uint4(g7, a);
        }
        float si = rsqrtf(fmaxf((float)dgraw, 1.0f));
        s16x8 ahi, alo;
#pragma unroll
        for (int j = 0; j < 8; j++) {
            float av = a[j] * si;
            unsigned short hh = f32_to_bf16_rtne(av);
            ahi[j] = (short)hh;
            alo[j] = (short)f32_to_bf16_rtne(av - bf16_to_f32(hh));
        }
        mHI[nloc * 17 + l] = ahi;
        mLO[nloc * 17 + l] = alo;
    }
    __syncthreads();

    // ---- phase 2: GEMM ----
    int wv = tid >> 6;                 // wave 0..3 -> col-tiles {2wv, 2wv+1}
    int lane = tid & 63;
    int arow = lane & 15, aq = lane >> 4;
    int ct0 = wv * 2, ct1 = ct0 + 1;
    f32x4 acc0 = (f32x4)0.f, acc1 = (f32x4)0.f;

#pragma unroll
    for (int ks = 0; ks < 4; ks++) {
        s16x8 ahi = mHI[arow * 17 + ks * 4 + aq];
        s16x8 alo = mLO[arow * 17 + ks * 4 + aq];
        int idx0 = (ct0 * 4 + ks) * 64 + lane;
        int idx1 = (ct1 * 4 + ks) * 64 + lane;
        s16x8 b0h = wpk[idx0], b0l = wpk[idx0 + 2048];
        s16x8 b1h = wpk[idx1], b1l = wpk[idx1 + 2048];
        acc0 = __builtin_amdgcn_mfma_f32_16x16x32_bf16(ahi, b0h, acc0, 0, 0, 0);
        acc0 = __builtin_amdgcn_mfma_f32_16x16x32_bf16(alo, b0h, acc0, 0, 0, 0);
        acc0 = __builtin_amdgcn_mfma_f32_16x16x32_bf16(ahi, b0l, acc0, 0, 0, 0);
        acc1 = __builtin_amdgcn_mfma_f32_16x16x32_bf16(ahi, b1h, acc1, 0, 0, 0);
        acc1 = __builtin_amdgcn_mfma_f32_16x16x32_bf16(alo, b1h, acc1, 0, 0, 0);
        acc1 = __builtin_amdgcn_mfma_f32_16x16x32_bf16(ahi, b1l, acc1, 0, 0, 0);
    }

    // C/D: col = lane&15, row = (lane>>4)*4 + reg
    int crow0 = aq * 4;
    float so4[4];
    if (outb) {
#pragma unroll
        for (int r = 0; r < 4; r++) so4[r] = s_out[row0 + crow0 + r];
    }
    int colA = ct0 * 16 + arow, colB = ct1 * 16 + arow;
    float bA = bias[colA], bB = bias[colB];
#pragma unroll
    for (int r = 0; r < 4; r++) {
        size_t rowoff = (size_t)(row0 + crow0 + r) * D;
        float vA = fmaxf(acc0[r] + bA, 0.f);
        float vB = fmaxf(acc1[r] + bB, 0.f);
        if (outf) { outf[rowoff + colA] = vA; outf[rowoff + colB] = vB; }
        if (outb) {
            outb[rowoff + colA] = f32_to_bf16_rtne(so4[r] * vA);
            outb[rowoff + colB] = f32_to_bf16_rtne(so4[r] * vB);
        }
    }
}

// ---------------- launch ----------------

extern "C" void kernel_launch(void* const* d_in, const int* in_sizes, int n_in,
                              void* d_out, int out_size, void* d_ws, size_t ws_size,
                              hipStream_t stream) {
    const float* h  = (const float*)d_in[0];
    const int*  src = (const int*)d_in[1];
    const int*  dst = (const int*)d_in[2];
    const float* W0 = (const float*)d_in[3];
    const float* b0 = (const float*)d_in[4];
    const float* W1 = (const float*)d_in[5];
    const float* b1 = (const float*)d_in[6];
    const float* W2 = (const float*)d_in[7];
    const float* b2 = (const float*)d_in[8];
    float* out = (float*)d_out;

    char* w = (char*)d_ws;
    auto carve = [&](size_t bytes) -> void* {
        void* p = (void*)w;
        w += (bytes + 255) & ~(size_t)255;
        return p;
    };
    int*      cursor  = (int*)carve(2 * N_NODES * sizeof(int));   // cursor + odeg, contiguous
    int*      odeg    = cursor + N_NODES;
    float*    s_out   = (float*)carve(N_NODES * sizeof(float));
    unsigned short* slots = (unsigned short*)carve((size_t)N_NODES * CAP * sizeof(unsigned short)); // 4.8 MB
    unsigned short* actA  = (unsigned short*)carve((size_t)(N_NODES + 1) * D * 2);  // 12.8 MB (+zero row)
    unsigned short* actB  = (unsigned short*)carve((size_t)(N_NODES + 1) * D * 2);  // 12.8 MB
    s16x8*    wpk     = (s16x8*)carve(3 * 4096 * sizeof(s16x8));                    // 192 KB

    hipMemsetAsync(cursor, 0, 2 * N_NODES * sizeof(int), stream);  // cursor + odeg
    build_fill<<<FILLB + PACKB, 256, 0, stream>>>(src, dst, cursor, odeg, slots,
                                                  W0, W1, W2, wpk);
    hconv<<<(N_NODES * 32 + 64 + 255) / 256, 256, 0, stream>>>((const float4*)h, odeg, s_out,
                                                               (uint2*)actA, (uint2*)actB);

    const int GRID = N_NODES / 16;   // 3125 exact

    // layer 1: actA(bf16, s_out-scaled h) -> actB
    fused_layer<<<GRID, 256, 0, stream>>>((const uint4*)actA, slots, cursor,
                                          wpk, b0, s_out, nullptr, actB);
    // layer 2: actB -> actA
    fused_layer<<<GRID, 256, 0, stream>>>((const uint4*)actB, slots, cursor,
                                          wpk + 4096, b1, s_out, nullptr, actA);
    // layer 3: actA -> d_out (fp32)
    fused_layer<<<GRID, 256, 0, stream>>>((const uint4*)actA, slots, cursor,
                                          wpk + 8192, b2, s_out, out, nullptr);
}

// Round 7
// 244.472 us; speedup vs baseline: 1.0856x; 1.0856x over previous
//
#include <hip/hip_runtime.h>

#define N_NODES 50000
#define N_EDGES 800000
#define D 128
#define CAP 48                        // max in-degree slots (verified sufficient R2-R8)

#define FILLB (N_EDGES / 256)         // 3125 fill blocks (exact), one edge per thread
#define PACKB 24                      // W-pack blocks (96 wids)

// ---- src-side binning for odeg (replay-safe: histogram is order-independent) ----
#define ABLK 400                      // binning blocks
#define AEDGES (N_EDGES / ABLK)       // 2000 edges per binning block (exact)
#define BW 512                        // bucket width (nodes); bucket = src>>9
#define NBUCK 98                      // ceil(50176/512)
#define BCAP 10240                    // per-bucket capacity (mean 8163, +23 sigma)

typedef __attribute__((ext_vector_type(4))) float f32x4;
typedef __attribute__((ext_vector_type(8))) short s16x8;

__device__ inline unsigned short f32_to_bf16_rtne(float f) {
    union { float f; unsigned u; } c; c.f = f;
    unsigned u = c.u;
    u += 0x7FFF + ((u >> 16) & 1);
    return (unsigned short)(u >> 16);
}
__device__ inline float bf16_to_f32(unsigned short h) {
    union { unsigned u; float f; } c; c.u = ((unsigned)h) << 16;
    return c.f;
}
__device__ inline unsigned pack_bf2(float a, float b) {
    return (unsigned)f32_to_bf16_rtne(a) | ((unsigned)f32_to_bf16_rtne(b) << 16);
}
__device__ inline void unpack_bf2(unsigned u, float& a, float& b) {
    union { unsigned u; float f; } c0, c1;
    c0.u = u << 16; c1.u = u & 0xFFFF0000u;
    a = c0.f; b = c1.f;
}
__device__ inline void acc_uint4(uint4 v, float* a) {
    float f0, f1;
    unpack_bf2(v.x, f0, f1); a[0] += f0; a[1] += f1;
    unpack_bf2(v.y, f0, f1); a[2] += f0; a[3] += f1;
    unpack_bf2(v.z, f0, f1); a[4] += f0; a[5] += f1;
    unpack_bf2(v.w, f0, f1); a[6] += f0; a[7] += f1;
}

// ---------------- build: slot fill (frozen ordering) | W-pack | src binning ----------------
// R0-R4 lessons: (1) scattered sub-line global ops (store OR atomic) cost ~40ns each
// (~32 G ops/s invariant across 4 structural variants); (2) slot-fill ORDERING is frozen
// (R4's reordered build tripped the replay numerics check); (3) odeg is a pure histogram
// -> order-independent -> safe to move off the atomic path. Fill role now does ONLY
// slot store + cursor atomic (2 scattered ops/edge -> 2... was 3). Binning role (R4's
// proven src path): clustered u16 stores into 98 bucket runs, histogrammed by odeg_hist.

__global__ __launch_bounds__(256) void build_fill(const int* __restrict__ src,
                                                  const int* __restrict__ dst,
                                                  int* __restrict__ cursor,
                                                  int* __restrict__ gcurS,
                                                  unsigned short* __restrict__ sbin,
                                                  unsigned short* __restrict__ slots,
                                                  const float* __restrict__ W0,
                                                  const float* __restrict__ W1,
                                                  const float* __restrict__ W2,
                                                  s16x8* __restrict__ wpk) {
    int b = blockIdx.x;
    if (b < FILLB) {
        int e = b * 256 + threadIdx.x;
        int s = src[e];
        int d = dst[e];
        int pos = atomicAdd(&cursor[d], 1);
        if (pos < CAP) slots[d * CAP + pos] = (unsigned short)s;
    } else if (b < FILLB + PACKB) {
        // ---- W-pack role ----
        int wid = (b - FILLB) * 4 + (threadIdx.x >> 6);   // 0..95 = layer(3) x ct(8) x ks(4)
        if (wid >= 96) return;
        int lane = threadIdx.x & 63;
        int layer = wid / 32, rem = wid % 32;
        int ct = rem >> 2, ks = rem & 3;
        const float* W = (layer == 0) ? W0 : (layer == 1) ? W1 : W2;
        int col = ct * 16 + (lane & 15);
        int k0  = ks * 32 + (lane >> 4) * 8;
        s16x8 hi, lo;
#pragma unroll
        for (int j = 0; j < 8; j++) {
            float w = W[(k0 + j) * D + col];
            unsigned short h = f32_to_bf16_rtne(w);
            hi[j] = (short)h;
            lo[j] = (short)f32_to_bf16_rtne(w - bf16_to_f32(h));
        }
        int idx = layer * 4096 + (ct * 4 + ks) * 64 + lane;
        wpk[idx]        = hi;
        wpk[idx + 2048] = lo;
    } else {
        // ---- src binning role (odeg precursor) ----
        int bb = b - FILLB - PACKB;                       // 0..399
        __shared__ int cntS[NBUCK], baseS[NBUCK], c2S[NBUCK];
        for (int i = threadIdx.x; i < NBUCK; i += 256) { cntS[i] = 0; c2S[i] = 0; }
        __syncthreads();
        int e0 = bb * AEDGES;
        for (int i = threadIdx.x; i < AEDGES; i += 256)
            atomicAdd(&cntS[src[e0 + i] >> 9], 1);
        __syncthreads();
        for (int i = threadIdx.x; i < NBUCK; i += 256)
            baseS[i] = atomicAdd(&gcurS[i], cntS[i]);
        __syncthreads();
        for (int i = threadIdx.x; i < AEDGES; i += 256) {
            int s = src[e0 + i];
            int bs = s >> 9;
            int rs = atomicAdd(&c2S[bs], 1);
            int os = baseS[bs] + rs;
            if (os < BCAP) sbin[bs * BCAP + os] = (unsigned short)s;
        }
    }
}

// ---------------- odeg: per-bucket LDS histogram of binned srcs (order-independent) ----------------

__global__ __launch_bounds__(512) void odeg_hist(const unsigned short* __restrict__ sbin,
                                                 const int* __restrict__ gcurS,
                                                 int* __restrict__ odeg) {
    int b = blockIdx.x;
    __shared__ int cnt[BW];
    for (int i = threadIdx.x; i < BW; i += 512) cnt[i] = 0;
    __syncthreads();
    int nE = min(gcurS[b], BCAP);
    const unsigned short* es = sbin + (size_t)b * BCAP;
    for (int i = threadIdx.x; i < nE; i += 512)
        atomicAdd(&cnt[es[i] & (BW - 1)], 1);
    __syncthreads();
    int n0 = b * BW;
    for (int i = threadIdx.x; i < BW; i += 512)
        if (n0 + i < N_NODES) odeg[n0 + i] = cnt[i];
}

// ---------------- h -> bf16 rows pre-scaled by s_out (computed in-kernel from odeg) ----------------

__global__ __launch_bounds__(256) void hconv(const float4* __restrict__ h,
                                             const int* __restrict__ odeg,
                                             float* __restrict__ s_out,
                                             uint2* __restrict__ hbA,
                                             uint2* __restrict__ hbB) {
    int gid = blockIdx.x * 256 + threadIdx.x;   // one float4 (4 channels) per thread
    const int total = N_NODES * 32;
    if (gid < total) {
        int node = gid >> 5;
        float so = rsqrtf(fmaxf((float)odeg[node], 1.0f));
        if ((gid & 31) == 0) s_out[node] = so;   // persist for fused_layer epilogue
        float4 v = h[gid];
        hbA[gid] = make_uint2(pack_bf2(so * v.x, so * v.y), pack_bf2(so * v.z, so * v.w));
    } else if (gid < total + 32) {
        hbA[total + (gid - total)] = make_uint2(0u, 0u);        // zero row of actA
    } else if (gid < total + 64) {
        hbB[total + (gid - total - 32)] = make_uint2(0u, 0u);   // zero row of actB
    }
}

// ---------------- fused layer: gather-aggregate -> LDS(split-bf16) -> MFMA GEMM ----------------

__global__ __launch_bounds__(256) void fused_layer(const uint4* __restrict__ x,
                                                   const unsigned short* __restrict__ slots,
                                                   const int* __restrict__ deg,
                                                   const s16x8* __restrict__ wpk,
                                                   const float* __restrict__ bias,
                                                   const float* __restrict__ s_out,
                                                   float* __restrict__ outf,
                                                   unsigned short* __restrict__ outb) {
    __shared__ s16x8 mHI[16 * 17];
    __shared__ s16x8 mLO[16 * 17];
    int tid = threadIdx.x;
    int row0 = blockIdx.x * 16;

    // ---- phase 1: aggregate ----
    {
        int nloc = tid >> 4;          // local node 0..15
        int l    = tid & 15;          // chunk: channels l*8 .. l*8+7
        int node = row0 + nloc;
        int dgraw = deg[node];
        int dg = min(dgraw, CAP);
        int base = node * CAP;
        // prefetch all slot indices; OOB -> zero row
        int idx0 = (l      < dg) ? (int)slots[base + l]      : N_NODES;
        int idx1 = (16 + l < dg) ? (int)slots[base + 16 + l] : N_NODES;
        int idx2 = (32 + l < dg) ? (int)slots[base + 32 + l] : N_NODES;

        float a[8];
#pragma unroll
        for (int j = 0; j < 8; j++) a[j] = 0.f;

        int nr = (dg + 7) >> 3;       // rounds of 8 (0..6), no tails
        for (int r = 0; r < nr; r++) {
            int c = r >> 1;
            int v = (c == 0) ? idx0 : ((c == 1) ? idx1 : idx2);
            int k = (r & 1) * 8;
            int s0 = __shfl(v, k + 0, 16), s1 = __shfl(v, k + 1, 16);
            int s2 = __shfl(v, k + 2, 16), s3 = __shfl(v, k + 3, 16);
            int s4 = __shfl(v, k + 4, 16), s5 = __shfl(v, k + 5, 16);
            int s6 = __shfl(v, k + 6, 16), s7 = __shfl(v, k + 7, 16);
            uint4 g0 = x[s0 * 16 + l];
            uint4 g1 = x[s1 * 16 + l];
            uint4 g2 = x[s2 * 16 + l];
            uint4 g3 = x[s3 * 16 + l];
            uint4 g4 = x[s4 * 16 + l];
            uint4 g5 = x[s5 * 16 + l];
            uint4 g6 = x[s6 * 16 + l];
            uint4 g7 = x[s7 * 16 + l];
            acc_uint4(g0, a); acc_uint4(g1, a); acc_uint4(g2, a); acc_uint4(g3, a);
            acc_uint4(g4, a); acc_uint4(g5, a); acc_uint4(g6, a); acc_uint4(g7, a);
        }
        float si = rsqrtf(fmaxf((float)dgraw, 1.0f));
        s16x8 ahi, alo;
#pragma unroll
        for (int j = 0; j < 8; j++) {
            float av = a[j] * si;
            unsigned short hh = f32_to_bf16_rtne(av);
            ahi[j] = (short)hh;
            alo[j] = (short)f32_to_bf16_rtne(av - bf16_to_f32(hh));
        }
        mHI[nloc * 17 + l] = ahi;
        mLO[nloc * 17 + l] = alo;
    }
    __syncthreads();

    // ---- phase 2: GEMM ----
    int wv = tid >> 6;                 // wave 0..3 -> col-tiles {2wv, 2wv+1}
    int lane = tid & 63;
    int arow = lane & 15, aq = lane >> 4;
    int ct0 = wv * 2, ct1 = ct0 + 1;
    f32x4 acc0 = (f32x4)0.f, acc1 = (f32x4)0.f;

#pragma unroll
    for (int ks = 0; ks < 4; ks++) {
        s16x8 ahi = mHI[arow * 17 + ks * 4 + aq];
        s16x8 alo = mLO[arow * 17 + ks * 4 + aq];
        int idx0 = (ct0 * 4 + ks) * 64 + lane;
        int idx1 = (ct1 * 4 + ks) * 64 + lane;
        s16x8 b0h = wpk[idx0], b0l = wpk[idx0 + 2048];
        s16x8 b1h = wpk[idx1], b1l = wpk[idx1 + 2048];
        acc0 = __builtin_amdgcn_mfma_f32_16x16x32_bf16(ahi, b0h, acc0, 0, 0, 0);
        acc0 = __builtin_amdgcn_mfma_f32_16x16x32_bf16(alo, b0h, acc0, 0, 0, 0);
        acc0 = __builtin_amdgcn_mfma_f32_16x16x32_bf16(ahi, b0l, acc0, 0, 0, 0);
        acc1 = __builtin_amdgcn_mfma_f32_16x16x32_bf16(ahi, b1h, acc1, 0, 0, 0);
        acc1 = __builtin_amdgcn_mfma_f32_16x16x32_bf16(alo, b1h, acc1, 0, 0, 0);
        acc1 = __builtin_amdgcn_mfma_f32_16x16x32_bf16(ahi, b1l, acc1, 0, 0, 0);
    }

    // C/D: col = lane&15, row = (lane>>4)*4 + reg
    int crow0 = aq * 4;
    float so4[4];
    if (outb) {
#pragma unroll
        for (int r = 0; r < 4; r++) so4[r] = s_out[row0 + crow0 + r];
    }
    int colA = ct0 * 16 + arow, colB = ct1 * 16 + arow;
    float bA = bias[colA], bB = bias[colB];
#pragma unroll
    for (int r = 0; r < 4; r++) {
        size_t rowoff = (size_t)(row0 + crow0 + r) * D;
        float vA = fmaxf(acc0[r] + bA, 0.f);
        float vB = fmaxf(acc1[r] + bB, 0.f);
        if (outf) { outf[rowoff + colA] = vA; outf[rowoff + colB] = vB; }
        if (outb) {
            outb[rowoff + colA] = f32_to_bf16_rtne(so4[r] * vA);
            outb[rowoff + colB] = f32_to_bf16_rtne(so4[r] * vB);
        }
    }
}

// ---------------- launch ----------------

extern "C" void kernel_launch(void* const* d_in, const int* in_sizes, int n_in,
                              void* d_out, int out_size, void* d_ws, size_t ws_size,
                              hipStream_t stream) {
    const float* h  = (const float*)d_in[0];
    const int*  src = (const int*)d_in[1];
    const int*  dst = (const int*)d_in[2];
    const float* W0 = (const float*)d_in[3];
    const float* b0 = (const float*)d_in[4];
    const float* W1 = (const float*)d_in[5];
    const float* b1 = (const float*)d_in[6];
    const float* W2 = (const float*)d_in[7];
    const float* b2 = (const float*)d_in[8];
    float* out = (float*)d_out;

    char* w = (char*)d_ws;
    auto carve = [&](size_t bytes) -> void* {
        void* p = (void*)w;
        w += (bytes + 255) & ~(size_t)255;
        return p;
    };
    int*      cursor  = (int*)carve((N_NODES + 128) * sizeof(int)); // cursor + gcurS (one memset)
    int*      gcurS   = cursor + N_NODES;
    int*      odeg    = (int*)carve(N_NODES * sizeof(int));         // fully written by odeg_hist
    float*    s_out   = (float*)carve(N_NODES * sizeof(float));
    unsigned short* slots = (unsigned short*)carve((size_t)N_NODES * CAP * sizeof(unsigned short)); // 4.8 MB
    unsigned short* sbin  = (unsigned short*)carve((size_t)NBUCK * BCAP * sizeof(unsigned short));  // 2.0 MB
    unsigned short* actA  = (unsigned short*)carve((size_t)(N_NODES + 1) * D * 2);  // 12.8 MB (+zero row)
    unsigned short* actB  = (unsigned short*)carve((size_t)(N_NODES + 1) * D * 2);  // 12.8 MB
    s16x8*    wpk     = (s16x8*)carve(3 * 4096 * sizeof(s16x8));                    // 192 KB

    hipMemsetAsync(cursor, 0, (N_NODES + 128) * sizeof(int), stream);  // cursor + gcurS
    build_fill<<<FILLB + PACKB + ABLK, 256, 0, stream>>>(src, dst, cursor, gcurS, sbin, slots,
                                                         W0, W1, W2, wpk);
    odeg_hist<<<NBUCK, 512, 0, stream>>>(sbin, gcurS, odeg);
    hconv<<<(N_NODES * 32 + 64 + 255) / 256, 256, 0, stream>>>((const float4*)h, odeg, s_out,
                                                               (uint2*)actA, (uint2*)actB);

    const int GRID = N_NODES / 16;   // 3125 exact

    // layer 1: actA(bf16, s_out-scaled h) -> actB
    fused_layer<<<GRID, 256, 0, stream>>>((const uint4*)actA, slots, cursor,
                                          wpk, b0, s_out, nullptr, actB);
    // layer 2: actB -> actA
    fused_layer<<<GRID, 256, 0, stream>>>((const uint4*)actB, slots, cursor,
                                          wpk + 4096, b1, s_out, nullptr, actA);
    // layer 3: actA -> d_out (fp32)
    fused_layer<<<GRID, 256, 0, stream>>>((const uint4*)actA, slots, cursor,
                                          wpk + 8192, b2, s_out, out, nullptr);
}